// Round 24
// baseline (481.213 us; speedup 1.0000x reference)
//
#include <hip/hip_runtime.h>

// PWC-Net cost volume, fp32. B=4, C=128, H=256, W=448, 81 shifts.
// out[b, di*9+dj, h, w] = (1/128) * sum_c feat1[b,c,h,w] * feat2[b,c,h+di-4,w+dj-4]
//
// R22 structure (best: 272us prof, DS-bound at 76% util) + BK=2: two
// channels per body -> 64 bodies, halving the per-body wait/barrier/issue
// slack (~300cy) that is 24% of runtime. Block = (b,h), 1024 thr / 16 waves.
// Thread owns ONE 4-px quad: it = tid -> di = it/112, G = it%112 (1008
// active). acc[9][4] = 36; arch VGPR ~60 -> no spill at cap 128.
//
// LDS: ring-3 of DOUBLE buffers (2 channels). Channel buffer = 10 rows x
// 114 atoms(16B): rows 0..8 = feat2 h-4..h+4 (OOB rows from zws), row 9 =
// feat1 h. Atoms 0/113 = halo, zeroed once, never staged. Thread reads f2
// atoms G..G+2 + f1 atom G+1 per channel (lane-stride-16B = free 2-way).
//
// Schedule: double-body T (channels 2T,2T+1): wait vmcnt(2*2nIss... i.e.
// leave bundle T+1 in flight, drain bundle T issued 2 double-bodies (4
// channels, ~2500cy) ago; barrier (publishes slot T%3; reads of slot
// (T-1)%3 are consumed pre-barrier); stage bundle T+2 -> slot (T+2)%3;
// compute both channels of slot T%3. Stage bundle = per wave 2*nIss issues
// (each descriptor: ch0 at sp, ch1 at sp+sstep; advance 2*sstep).

typedef __attribute__((ext_vector_type(4))) float f32x4;

#define GLAS(p) ((const __attribute__((address_space(1))) unsigned int*)(p))
#define LDAS(p) ((__attribute__((address_space(3))) unsigned int*)(p))

__global__ __launch_bounds__(1024, 4) void cv_kernel(
    const float* __restrict__ feat1,
    const float* __restrict__ feat2,
    const float* __restrict__ zws,
    float* __restrict__ out)
{
    constexpr int C = 128, H = 256, W = 448;
    constexpr size_t HW = (size_t)H * W;
    constexpr int ROWB = 114 * 16;     // 1824 B
    constexpr int BUFB = 10 * ROWB;    // 18240 B (one channel)
    constexpr int DBUF = 2 * BUFB;     // 36480 B (double buffer)
    __shared__ __align__(16) char f2s[3 * DBUF];   // 109440 B

    const int tid  = threadIdx.x;
    const int wid  = tid >> 6;
    const int lane = tid & 63;

    // XCD-contiguous (b,h) mapping (1024 = 8*128, bijective)
    const int lin = (blockIdx.x & 7) * 128 + (blockIdx.x >> 3);
    const int b = lin >> 8, h = lin & 255;

    const int it = (tid < 1008) ? tid : 1007;
    const int di = it / 112;
    const int G  = it - di * 112;      // 0..111

    // Zero LDS once (halo atoms 0/113 of all 6 channel-buffers persist).
    for (int i = tid; i < (int)sizeof(f2s) / 16; i += 1024)
        *(f32x4*)(f2s + i * 16) = (f32x4){0.f, 0.f, 0.f, 0.f};

    // Staging descriptors. Issue j: row r = j>>1 (0..9), half hf = j&1.
    // Lanes 0..55: 16B from row_base + hf*224 + lane*4 floats
    //   -> dest r*ROWB + 16 + hf*896 (atoms 1..112 linear).
    // r==9 -> feat1 row h; else feat2 row h+r-4 (OOB -> zws, step 0).
    const int nIss = (wid < 4) ? 2 : 1;
    const float* sp[2]; unsigned sstep[2]; int sdst[2];
#pragma unroll
    for (int k = 0; k < 2; ++k) {
        if (k < nIss) {
            const int j  = wid + 16 * k;
            const int r  = j >> 1, hf = j & 1;
            const int colf = hf * 224 + ((lane < 56) ? lane * 4 : 220);
            if (r == 9) {
                sp[k] = feat1 + ((size_t)b * C * H + (size_t)h) * W + colf;
                sstep[k] = (unsigned)HW;
            } else {
                const int hr = h + r - 4;
                const bool ok = (hr >= 0) && (hr < H);
                sp[k] = ok ? (feat2 + ((size_t)b * C * H + (size_t)hr) * W + colf) : zws;
                sstep[k] = ok ? (unsigned)HW : 0u;
            }
            sdst[k] = r * ROWB + 16 + hf * 896;
        }
    }

    // Read offsets: f2 atoms G..G+2 of row di; f1 atom G+1 of row 9.
    const int r2o = di * ROWB + G * 16;
    const int r1o = 9 * ROWB + (G + 1) * 16;

    float acc[9][4];
#pragma unroll
    for (int j = 0; j < 9; ++j)
#pragma unroll
        for (int p = 0; p < 4; ++p) acc[j][p] = 0.0f;

    __syncthreads();   // LDS zeros visible before first stage lands

// Stage double-bundle into ring slot (both channels of each descriptor).
#define STAGE2(SLOTOFS) do { \
    _Pragma("unroll") \
    for (int k = 0; k < 2; ++k) { \
        if (k < nIss) { \
            if (lane < 56) { \
                __builtin_amdgcn_global_load_lds(GLAS(sp[k]), \
                    LDAS(f2s + (SLOTOFS) + sdst[k]), 16, 0, 0); \
                __builtin_amdgcn_global_load_lds(GLAS(sp[k] + sstep[k]), \
                    LDAS(f2s + (SLOTOFS) + BUFB + sdst[k]), 16, 0, 0); \
            } \
            sp[k] += 2 * sstep[k]; \
        } \
    } } while (0)

#define COMP1(CBOFS) do { \
    const char* lb = f2s + (CBOFS); \
    const f32x4 L  = *(const f32x4*)(lb + r2o); \
    const f32x4 Cq = *(const f32x4*)(lb + r2o + 16); \
    const f32x4 R  = *(const f32x4*)(lb + r2o + 32); \
    const f32x4 A  = *(const f32x4*)(lb + r1o); \
    const float w[12] = {L.x, L.y, L.z, L.w, Cq.x, Cq.y, Cq.z, Cq.w, \
                         R.x, R.y, R.z, R.w}; \
    const float a[4] = {A.x, A.y, A.z, A.w}; \
    _Pragma("unroll") \
    for (int dj = 0; dj < 9; ++dj) { \
        _Pragma("unroll") \
        for (int p = 0; p < 4; ++p) \
            acc[dj][p] = fmaf(a[p], w[dj + p], acc[dj][p]); \
    } } while (0)

// MODE 0: wait 2n + stage | 1: wait 2n, no stage | 2: wait 0, no stage
#define BODY(SLOT, NSLOT, MODE) do { \
    if ((MODE) <= 1) { \
        if (wid < 4) asm volatile("s_waitcnt vmcnt(4)" ::: "memory"); \
        else         asm volatile("s_waitcnt vmcnt(2)" ::: "memory"); \
    } else { \
        asm volatile("s_waitcnt vmcnt(0)" ::: "memory"); \
    } \
    __builtin_amdgcn_s_barrier(); \
    __builtin_amdgcn_sched_barrier(0); \
    if ((MODE) == 0) STAGE2((NSLOT) * DBUF); \
    COMP1((SLOT) * DBUF); \
    COMP1((SLOT) * DBUF + BUFB); \
  } while (0)

    // Prologue: double-bundles 0,1 into slots 0,1 (2 bundles outstanding).
    STAGE2(0 * DBUF);
    STAGE2(1 * DBUF);

    // Double-bodies 0..61 stage T+2; tails 62 (wait 2n), 63 (wait 0).
#pragma unroll 1
    for (int g = 0; g < 20; ++g) {
        BODY(0, 2, 0);
        BODY(1, 0, 0);
        BODY(2, 1, 0);
    }
    BODY(0, 2, 0);   // T=60: stages bundle 62 -> slot 2
    BODY(1, 0, 0);   // T=61: stages bundle 63 -> slot 0
    BODY(2, 1, 1);   // T=62: drains bundle 62, leaves 63
    BODY(0, 1, 2);   // T=63: wait 0

#undef STAGE2
#undef COMP1
#undef BODY

    if (tid < 1008) {
        const float s = 1.0f / 128.0f;
        float* ob = out + (((size_t)(b * 81 + di * 9)) * H + h) * W + G * 4;
#pragma unroll
        for (int dj = 0; dj < 9; ++dj) {
            f32x4 ov = {acc[dj][0] * s, acc[dj][1] * s,
                        acc[dj][2] * s, acc[dj][3] * s};
            *(f32x4*)(ob + (size_t)dj * HW) = ov;
        }
    }
}

extern "C" void kernel_launch(void* const* d_in, const int* in_sizes, int n_in,
                              void* d_out, int out_size, void* d_ws, size_t ws_size,
                              hipStream_t stream) {
    const float* feat1 = (const float*)d_in[0];
    const float* feat2 = (const float*)d_in[1];
    float* out = (float*)d_out;
    // 256 zeroed bytes: broadcast-source for vertically-OOB feat2 rows.
    hipMemsetAsync(d_ws, 0, 256, stream);
    cv_kernel<<<dim3(1024), dim3(1024), 0, stream>>>(
        feat1, feat2, (const float*)d_ws, out);
}

// Round 25
// 243.398 us; speedup vs baseline: 1.9771x; 1.9771x over previous
//
#include <hip/hip_runtime.h>

// PWC-Net cost volume, fp32. B=4, C=128, H=256, W=448, 81 shifts.
// out[b, di*9+dj, h, w] = (1/128) * sum_c feat1[b,c,h,w] * feat2[b,c,h+di-4,w+dj-4]
//
// R22 schedule (ring-4, leave-2 counted vmcnt, 272us) with HALF-WIDTH blocks:
// block = (b,h,half), 512 thr / 8 waves, 2048 blocks. Two such blocks fit a
// CU (regs ~96 -> 5 waves/SIMD; LDS 38.4KB*2 = 77KB) -> TWO independent
// barrier domains per CU, so one block's DS burst overlaps the other's FMA/
// wait phase (R22 was a single 16-wave domain -> convoy slack ~300cy/body).
//
// Thread owns ONE 4-px quad of its half: it = tid -> di = it/56, mq = it%56
// (504 active), G = half*56 + mq. acc[9][4] = 36.
//
// LDS: ring-4 of channel buffers, 10 rows x 60 slots(16B). Rows 0..8 = feat2
// h-4..h+4, row 9 = feat1 h. Slot s of a row = atom A0+s, A0 = half*56
// (atom a covers cols 4a-4..4a-1). Halo (atom 0 / 113 -> slot 0 / 57) zeroed
// once, never staged -> edges free. Thread reads f2 slots mq,mq+1,mq+2 of
// row di + f1 slot mq+1 of row 9: lane-stride-16B -> free 2-way aliasing.
//
// Stage = 10 wave-issues/channel (1 per row, lanes 0..56):
//   half=0: dest slots 1..57 <- cols 4l       (atoms 1..57)
//   half=1: dest slots 0..56 <- cols 220+4l   (atoms 56..112)
// r==9 -> feat1 row h; else feat2 row h+r-4 (OOB -> zws, step 0).
// Wave wid: j = wid (+ 8+wid if wid<2); nIss = wid<2 ? 2 : 1.
//
// Body T: wait vmcnt(2*nIss) [drains bundle T, issued 3 bodies (~1800cy)
// ago; leaves T+1, T+2]; barrier; stage bundle T+3 -> buf (T+3)&3; compute
// buf T&3. Tails 125/126/127: wait 2n / n / 0.

typedef __attribute__((ext_vector_type(4))) float f32x4;

#define GLAS(p) ((const __attribute__((address_space(1))) unsigned int*)(p))
#define LDAS(p) ((__attribute__((address_space(3))) unsigned int*)(p))

__global__ __launch_bounds__(512, 4) void cv_kernel(
    const float* __restrict__ feat1,
    const float* __restrict__ feat2,
    const float* __restrict__ zws,
    float* __restrict__ out)
{
    constexpr int C = 128, H = 256, W = 448;
    constexpr size_t HW = (size_t)H * W;
    constexpr int ROWB = 60 * 16;      // 960 B
    constexpr int BUFB = 10 * ROWB;    // 9600 B
    __shared__ __align__(16) char f2s[4 * BUFB];   // 38400 B

    const int tid  = threadIdx.x;
    const int wid  = tid >> 6;
    const int lane = tid & 63;

    // XCD-contiguous mapping (2048 = 8*256, bijective); both halves of a
    // (b,h) and h-neighbors stay on one XCD -> f2 rows L2-shared.
    const int lin  = (blockIdx.x & 7) * 256 + (blockIdx.x >> 3);
    const int half = lin & 1;
    const int bh   = lin >> 1;
    const int h    = bh & 255, b = bh >> 8;

    const int it = (tid < 504) ? tid : 503;
    const int di = it / 56;
    const int mq = it - di * 56;       // 0..55

    // Zero LDS once (halo slots persist; staged slots overwritten each use).
    for (int i = tid; i < (int)sizeof(f2s) / 16; i += 512)
        *(f32x4*)(f2s + i * 16) = (f32x4){0.f, 0.f, 0.f, 0.f};

    // Staging descriptors. Issue j = row r (0..9). Lanes 0..56 load 16B:
    //   half=0: col 4*lane      -> dest slot 1+lane
    //   half=1: col 220+4*lane  -> dest slot lane
    const int nIss = (wid < 2) ? 2 : 1;
    const float* sp[2]; unsigned sstep[2]; int sdst[2];
#pragma unroll
    for (int k = 0; k < 2; ++k) {
        if (k < nIss) {
            const int r = wid + 8 * k;
            const int colf = (half ? 220 : 0) + ((lane < 57) ? lane * 4 : 0);
            if (r == 9) {
                sp[k] = feat1 + ((size_t)b * C * H + (size_t)h) * W + colf;
                sstep[k] = (unsigned)HW;
            } else {
                const int hr = h + r - 4;
                const bool ok = (hr >= 0) && (hr < H);
                sp[k] = ok ? (feat2 + ((size_t)b * C * H + (size_t)hr) * W + colf) : zws;
                sstep[k] = ok ? (unsigned)HW : 0u;
            }
            sdst[k] = r * ROWB + (half ? 0 : 16);
        }
    }

    // Read offsets: f2 slots mq..mq+2 of row di; f1 slot mq+1 of row 9.
    const int r2o = di * ROWB + mq * 16;
    const int r1o = 9 * ROWB + (mq + 1) * 16;

    float acc[9][4];
#pragma unroll
    for (int j = 0; j < 9; ++j)
#pragma unroll
        for (int p = 0; p < 4; ++p) acc[j][p] = 0.0f;

    __syncthreads();   // LDS zeros visible before first stage lands

#define STAGE(BUFOFS) do { \
    _Pragma("unroll") \
    for (int k = 0; k < 2; ++k) { \
        if (k < nIss) { \
            if (lane < 57) \
                __builtin_amdgcn_global_load_lds(GLAS(sp[k]), \
                    LDAS(f2s + (BUFOFS) + sdst[k]), 16, 0, 0); \
            sp[k] += sstep[k]; \
        } \
    } } while (0)

// MODE 0: wait 2n + stage | 1: wait 2n | 2: wait n | 3: wait 0
#define BODY(BUF, NBUF, MODE) do { \
    if ((MODE) <= 1) { \
        if (wid < 2) asm volatile("s_waitcnt vmcnt(4)" ::: "memory"); \
        else         asm volatile("s_waitcnt vmcnt(2)" ::: "memory"); \
    } else if ((MODE) == 2) { \
        if (wid < 2) asm volatile("s_waitcnt vmcnt(2)" ::: "memory"); \
        else         asm volatile("s_waitcnt vmcnt(1)" ::: "memory"); \
    } else { \
        asm volatile("s_waitcnt vmcnt(0)" ::: "memory"); \
    } \
    __builtin_amdgcn_s_barrier(); \
    __builtin_amdgcn_sched_barrier(0); \
    if ((MODE) == 0) STAGE((NBUF) * BUFB); \
    { \
        const char* lb = f2s + (BUF) * BUFB; \
        const f32x4 L  = *(const f32x4*)(lb + r2o); \
        const f32x4 Cq = *(const f32x4*)(lb + r2o + 16); \
        const f32x4 R  = *(const f32x4*)(lb + r2o + 32); \
        const f32x4 A  = *(const f32x4*)(lb + r1o); \
        const float w[12] = {L.x, L.y, L.z, L.w, Cq.x, Cq.y, Cq.z, Cq.w, \
                             R.x, R.y, R.z, R.w}; \
        const float a[4] = {A.x, A.y, A.z, A.w}; \
        _Pragma("unroll") \
        for (int dj = 0; dj < 9; ++dj) { \
            _Pragma("unroll") \
            for (int p = 0; p < 4; ++p) \
                acc[dj][p] = fmaf(a[p], w[dj + p], acc[dj][p]); \
        } \
    } } while (0)

    // Prologue: bundles 0,1,2 into buffers 0,1,2 (3 outstanding).
    STAGE(0 * BUFB);
    STAGE(1 * BUFB);
    STAGE(2 * BUFB);

    // Bodies 0..124 stage T+3; tails 125 (wait 2n), 126 (wait n), 127 (0).
#pragma unroll 1
    for (int g = 0; g < 31; ++g) {
        BODY(0, 3, 0);
        BODY(1, 0, 0);
        BODY(2, 1, 0);
        BODY(3, 2, 0);
    }
    BODY(0, 3, 0);   // T=124: stages bundle 127 -> buf 3
    BODY(1, 0, 1);   // T=125
    BODY(2, 1, 2);   // T=126
    BODY(3, 2, 3);   // T=127

#undef STAGE
#undef BODY

    if (tid < 504) {
        const float s = 1.0f / 128.0f;
        const int G = half * 56 + mq;
        float* ob = out + (((size_t)(b * 81 + di * 9)) * H + h) * W + G * 4;
#pragma unroll
        for (int dj = 0; dj < 9; ++dj) {
            f32x4 ov = {acc[dj][0] * s, acc[dj][1] * s,
                        acc[dj][2] * s, acc[dj][3] * s};
            *(f32x4*)(ob + (size_t)dj * HW) = ov;
        }
    }
}

extern "C" void kernel_launch(void* const* d_in, const int* in_sizes, int n_in,
                              void* d_out, int out_size, void* d_ws, size_t ws_size,
                              hipStream_t stream) {
    const float* feat1 = (const float*)d_in[0];
    const float* feat2 = (const float*)d_in[1];
    float* out = (float*)d_out;
    // 1 KiB zeros: stage source for vertically-OOB feat2 rows (lane*4 floats).
    hipMemsetAsync(d_ws, 0, 1024, stream);
    cv_kernel<<<dim3(2048), dim3(512), 0, stream>>>(
        feat1, feat2, (const float*)d_ws, out);
}